// Round 11
// baseline (258.310 us; speedup 1.0000x reference)
//
#include <hip/hip_runtime.h>
#include <hip/hip_bf16.h>

#define B_   2
#define S_   2048
#define DM   1024
#define NH   16
#define DKH  64
#define Mdim 4096
#define Ndim 1024
#define Kdim 1024

typedef __attribute__((ext_vector_type(8))) short bf16x8;
typedef __attribute__((ext_vector_type(4))) short bf16x4;
typedef __attribute__((ext_vector_type(4))) float f32x4;
typedef __attribute__((ext_vector_type(16))) float f32x16;

__device__ __forceinline__ short f2b(float x) {
  union { __hip_bfloat16 h; short s; } u;
  u.h = __float2bfloat16(x);
  return u.s;
}

// async global->LDS, 16 B/lane; LDS dst = wave-uniform base + lane*16
__device__ __forceinline__ void async_copy16(const void* g, void* l) {
  __builtin_amdgcn_global_load_lds(
      (const __attribute__((address_space(1))) unsigned int*)g,
      (__attribute__((address_space(3))) unsigned int*)l, 16, 0, 0);
}
// async global->LDS, 4 B/lane; LDS dst = wave-uniform base + lane*4
__device__ __forceinline__ void async_copy4(const void* g, void* l) {
  __builtin_amdgcn_global_load_lds(
      (const __attribute__((address_space(1))) unsigned int*)g,
      (__attribute__((address_space(3))) unsigned int*)l, 4, 0, 0);
}

// ---------------------------------------------------------------------------
// Batched fp32 -> bf16 conversion (7 tensors) + mask bit-pack (8th slice).
// Mask pack: mbT[kw * (B*S) + (b*S + q)], bit j = key kw*64 + j.
struct Cvt7 {
  const float* src[7];
  ushort* dst[7];
  int n[7];
};

__global__ __launch_bounds__(256) void cvt_all(Cvt7 c, const int* __restrict__ mask,
                                               unsigned long long* __restrict__ mb) {
  const int ten = blockIdx.y;
  if (ten == 7) {
#pragma unroll
    for (int it = 0; it < 16; ++it) {
      const size_t i = ((size_t)blockIdx.x * 16 + it) * 256 + threadIdx.x;
      const unsigned long long bits = __ballot(mask[i] != 0);
      if ((threadIdx.x & 63) == 0) {
        const size_t word = i >> 6;          // (b*S+q)*32 + kw
        const size_t kw = word & 31;
        const size_t row = word >> 5;        // b*S + q
        mb[kw * (size_t)(B_ * S_) + row] = bits;
      }
    }
    return;
  }
  const int base = (blockIdx.x * 256 + threadIdx.x) * 8;
  if (base >= c.n[ten]) return;
  const float* s = c.src[ten] + base;
  float4 a = *(const float4*)s;
  float4 b = *(const float4*)(s + 4);
  bf16x8 r;
  r[0] = f2b(a.x); r[1] = f2b(a.y); r[2] = f2b(a.z); r[3] = f2b(a.w);
  r[4] = f2b(b.x); r[5] = f2b(b.y); r[6] = f2b(b.z); r[7] = f2b(b.w);
  *(bf16x8*)(c.dst[ten] + base) = r;
}

// ---------------------------------------------------------------------------
__device__ __forceinline__ void gstore(float* C, size_t i, float v) { C[i] = v; }
__device__ __forceinline__ void gstore(ushort* C, size_t i, float v) { C[i] = (ushort)f2b(v); }

// C[4096,1024] = A@W^T + bias, *scale. 128x128 tile, BK=32, TRIPLE-buffered
// LDS via global_load_lds(16B); single barrier/iter, steady vmcnt(4).
// vt=1: epilogue transposes the tile through LDS -> coalesced [b][h][d][s].
template <typename OutT>
__device__ __forceinline__ void gemm_core(const ushort* __restrict__ A,
                                          const ushort* __restrict__ W,
                                          const float* __restrict__ bias,
                                          OutT* __restrict__ C, float scale, int vt,
                                          ushort* smem) {
  const int t = threadIdx.x;
  const int w = t >> 6, lane = t & 63;
  const int quad = lane >> 4, r16 = lane & 15;
  const int wr = w >> 1, wc = w & 1;
  const int row0 = blockIdx.x * 128, col0 = blockIdx.y * 128;

  ushort* a_s = smem;            // 3 bufs x 4096
  ushort* b_s = smem + 12288;    // 3 bufs x 4096

  const int sr = t >> 2, sc = (t & 3) * 8;
  const ushort* Ag0 = A + (size_t)(row0 + sr) * Kdim + sc;
  const ushort* Ag1 = Ag0 + (size_t)64 * Kdim;
  const ushort* Wg0 = W + (size_t)(col0 + sr) * Kdim + sc;
  const ushort* Wg1 = Wg0 + (size_t)64 * Kdim;
  const int alo0 = (w * 16) * 32;
  const int alo1 = (64 + w * 16) * 32;

  auto stg = [&](int buf, int k0) {
    ushort* ab = a_s + buf * 4096;
    ushort* bb = b_s + buf * 4096;
    async_copy16(Ag0 + k0, ab + alo0);
    async_copy16(Ag1 + k0, ab + alo1);
    async_copy16(Wg0 + k0, bb + alo0);
    async_copy16(Wg1 + k0, bb + alo1);
  };

  f32x4 acc[4][4];
#pragma unroll
  for (int mt = 0; mt < 4; ++mt)
#pragma unroll
    for (int nt = 0; nt < 4; ++nt) acc[mt][nt] = (f32x4){0.f, 0.f, 0.f, 0.f};

  stg(0, 0);
  stg(1, 32);
  for (int k0 = 0; k0 < Kdim; k0 += 32) {
    const int cb = (k0 >> 5) % 3;
    if (k0 + 32 < Kdim) {
      asm volatile("s_waitcnt vmcnt(4)" ::: "memory");
    } else {
      asm volatile("s_waitcnt vmcnt(0)" ::: "memory");
    }
    asm volatile("s_waitcnt lgkmcnt(0)" ::: "memory");
    __builtin_amdgcn_s_barrier();
    if (k0 + 64 < Kdim) stg((cb + 2) % 3, k0 + 64);

    const int bo = cb * 4096;
    bf16x8 af[4], bfr[4];
#pragma unroll
    for (int mt = 0; mt < 4; ++mt)
      af[mt] = *(const bf16x8*)&a_s[bo + (wr * 64 + mt * 16 + r16) * 32 + quad * 8];
#pragma unroll
    for (int nt = 0; nt < 4; ++nt)
      bfr[nt] = *(const bf16x8*)&b_s[bo + (wc * 64 + nt * 16 + r16) * 32 + quad * 8];
#pragma unroll
    for (int mt = 0; mt < 4; ++mt)
#pragma unroll
      for (int nt = 0; nt < 4; ++nt)
        acc[mt][nt] = __builtin_amdgcn_mfma_f32_16x16x32_bf16(af[mt], bfr[nt],
                                                              acc[mt][nt], 0, 0, 0);
  }

  if (vt) {
    __syncthreads();
    ushort* ts = smem;               // 128*136 ushorts <= 24576
#pragma unroll
    for (int mt = 0; mt < 4; ++mt) {
#pragma unroll
      for (int nt = 0; nt < 4; ++nt) {
        const int col_l = wc * 64 + nt * 16 + r16;
        const float bv = bias[col0 + col_l];
        const int row_l = wr * 64 + mt * 16 + quad * 4;
        bf16x4 pk;
#pragma unroll
        for (int i = 0; i < 4; ++i) pk[i] = f2b((acc[mt][nt][i] + bv) * scale);
        *(bf16x4*)&ts[col_l * 136 + row_l] = pk;
      }
    }
    __syncthreads();
    const int cch = (t & 15) * 8;
    const int rb = t >> 4;
#pragma unroll
    for (int pass = 0; pass < 8; ++pass) {
      const int col_l = rb + pass * 16;
      const bf16x8 v = *(const bf16x8*)&ts[col_l * 136 + cch];
      const int col_g = col0 + col_l;
      const int hh = col_g >> 6, dd = col_g & 63;
      const int row_g = row0 + cch;
      const int bb = row_g >> 11, ss = row_g & (S_ - 1);
      *(bf16x8*)&((ushort*)C)[(((size_t)bb * NH + hh) * 64 + dd) * S_ + ss] = v;
    }
    return;
  }

#pragma unroll
  for (int mt = 0; mt < 4; ++mt) {
#pragma unroll
    for (int nt = 0; nt < 4; ++nt) {
      const int col = col0 + wc * 64 + nt * 16 + r16;
      const float bv = bias[col];
      const int rowb = row0 + wr * 64 + mt * 16 + quad * 4;
#pragma unroll
      for (int i = 0; i < 4; ++i) {
        const float v = (acc[mt][nt][i] + bv) * scale;
        gstore(C, (size_t)(rowb + i) * Ndim + col, v);
      }
    }
  }
}

struct G3 {
  const ushort* A[3];
  const ushort* W[3];
  const float* bias[3];
  ushort* C[3];
  float scale[3];
};

__global__ __launch_bounds__(256) void gemm_qkv(G3 g) {
  __shared__ alignas(16) ushort smem[24576];  // 48 KB
  const int z = blockIdx.z;
  gemm_core<ushort>(g.A[z], g.W[z], g.bias[z], g.C[z], g.scale[z], z == 2, smem);
}

// ---------------------------------------------------------------------------
// O projection: 128x64 tile, BK=32, triple-buffered, single barrier/iter.
template <typename OutT>
__global__ __launch_bounds__(256) void gemm128(const ushort* __restrict__ A,
                                               const ushort* __restrict__ W,
                                               const float* __restrict__ bias,
                                               OutT* __restrict__ C, float scale) {
  const int t = threadIdx.x;
  const int w = t >> 6, lane = t & 63;
  const int quad = lane >> 4, r16 = lane & 15;
  const int wr = w >> 1, wc = w & 1;
  const int row0 = blockIdx.x * 128, col0 = blockIdx.y * 64;

  __shared__ alignas(16) ushort smem[18432];  // A 3x4096 | B 3x2048
  ushort* a_s = smem;
  ushort* b_s = smem + 12288;

  const int sr = lane >> 2, sc = (lane & 3) * 8;
  const ushort* Ag0 = A + (size_t)(row0 + w * 32 + sr) * Kdim + sc;
  const ushort* Ag1 = Ag0 + (size_t)16 * Kdim;
  const ushort* Wg  = W + (size_t)(col0 + w * 16 + sr) * Kdim + sc;
  const int al0 = (w * 32) * 32;
  const int al1 = (w * 32 + 16) * 32;
  const int bl  = (w * 16) * 32;

  auto stg = [&](int buf, int k0) {
    async_copy16(Ag0 + k0, &a_s[buf * 4096 + al0]);
    async_copy16(Ag1 + k0, &a_s[buf * 4096 + al1]);
    async_copy16(Wg + k0, &b_s[buf * 2048 + bl]);
  };

  f32x4 acc[4][2];
#pragma unroll
  for (int mt = 0; mt < 4; ++mt)
#pragma unroll
    for (int nt = 0; nt < 2; ++nt) acc[mt][nt] = (f32x4){0.f, 0.f, 0.f, 0.f};

  stg(0, 0);
  stg(1, 32);
  for (int k0 = 0; k0 < Kdim; k0 += 32) {
    const int cb = (k0 >> 5) % 3;
    if (k0 + 32 < Kdim) {
      asm volatile("s_waitcnt vmcnt(3)" ::: "memory");
    } else {
      asm volatile("s_waitcnt vmcnt(0)" ::: "memory");
    }
    asm volatile("s_waitcnt lgkmcnt(0)" ::: "memory");
    __builtin_amdgcn_s_barrier();
    if (k0 + 64 < Kdim) stg((cb + 2) % 3, k0 + 64);

    bf16x8 af[4], bfr[2];
#pragma unroll
    for (int mt = 0; mt < 4; ++mt)
      af[mt] = *(const bf16x8*)&a_s[cb * 4096 + (wr * 64 + mt * 16 + r16) * 32 + quad * 8];
#pragma unroll
    for (int nt = 0; nt < 2; ++nt)
      bfr[nt] = *(const bf16x8*)&b_s[cb * 2048 + (wc * 32 + nt * 16 + r16) * 32 + quad * 8];
#pragma unroll
    for (int mt = 0; mt < 4; ++mt)
#pragma unroll
      for (int nt = 0; nt < 2; ++nt)
        acc[mt][nt] = __builtin_amdgcn_mfma_f32_16x16x32_bf16(af[mt], bfr[nt],
                                                              acc[mt][nt], 0, 0, 0);
  }

#pragma unroll
  for (int mt = 0; mt < 4; ++mt) {
#pragma unroll
    for (int nt = 0; nt < 2; ++nt) {
      const int col = col0 + wc * 32 + nt * 16 + r16;
      const float bv = bias[col];
      const int rowb = row0 + wr * 64 + mt * 16 + quad * 4;
#pragma unroll
      for (int i = 0; i < 4; ++i) {
        const float v = (acc[mt][nt][i] + bv) * scale;
        gstore(C, (size_t)(rowb + i) * Ndim + col, v);
      }
    }
  }
}

// ---------------------------------------------------------------------------
// MFMA flash attention, 32x32x16, swapped QK^T, permlane exchange.
// Round-8 known-good version: 256 threads / 4 waves, triple-buffered
// K/V+mask via global_load_lds, counted vmcnt (10/5/0) across raw barriers,
// XCD head-grouping (K/V L2-resident), mask bias folded into QK^T C-init.
__global__ __launch_bounds__(256, 2) void attn_mfma(const ushort* __restrict__ Qp,
                                                    const ushort* __restrict__ Kp,
                                                    const ushort* __restrict__ Vt,
                                                    const unsigned long long* __restrict__ mbT,
                                                    ushort* __restrict__ Oa) {
  // bid = xcd + 8*m; head-group = xcd*4 + (m&3); q-block = m>>2
  const int bid = blockIdx.x;
  const int xcd = bid & 7, m = bid >> 3;
  const int bh = xcd * 4 + (m & 3);
  const int b = bh >> 4, h = bh & 15;
  const int q0 = (m >> 2) * 128;
  const int t = threadIdx.x;
  const int w = t >> 6, lane = t & 63;
  const int l31 = lane & 31, hi = lane >> 5, l7 = lane & 7;
  const size_t rbq = (size_t)b * S_;

  // [buf][row][chunk], 16B chunks XOR-swizzled: slot = c ^ (row&7)
  __shared__ alignas(16) ushort k_s[3][64 * 64];   // [key][dk]
  __shared__ alignas(16) ushort vt_s[3][64 * 64];  // [dk][key]
  __shared__ alignas(8) unsigned long long mask_lds[3][128];

  // Q B-frags: qf[s] holds Q[qrow][dk = 16s + 8hi + j]
  const int qrow = q0 + w * 32 + l31;
  const ushort* qp = Qp + (rbq + qrow) * DM + h * 64 + hi * 8;
  bf16x8 qf[4];
#pragma unroll
  for (int s = 0; s < 4; ++s) qf[s] = *(const bf16x8*)(qp + 16 * s);

  // staging: lane l -> LDS row base+(l>>3), slot l&7; global chunk pre-swizzled
  const int srow = lane >> 3;
  const int schk = l7 ^ srow;
  const int kr0 = w * 16 + srow;
  const ushort* kg0 = Kp + (rbq + kr0) * DM + h * 64 + schk * 8;
  const ushort* kg1 = kg0 + (size_t)8 * DM;
  const ushort* vg0 = Vt + ((size_t)bh * 64 + kr0) * S_ + schk * 8;
  const ushort* vg1 = vg0 + (size_t)8 * S_;
  const int lo0 = (w * 16) * 64;
  const int lo1 = (w * 16 + 8) * 64;
  const uint* mgsrc = (const uint*)mbT + ((size_t)b * S_ + q0) * 2 + t;

  auto stage = [&](int buf, int ktg) {
    async_copy16(kg0 + (size_t)ktg * DM, &k_s[buf][lo0]);
    async_copy16(kg1 + (size_t)ktg * DM, &k_s[buf][lo1]);
    async_copy16(vg0 + ktg, &vt_s[buf][lo0]);
    async_copy16(vg1 + ktg, &vt_s[buf][lo1]);
    async_copy4(mgsrc + (size_t)(ktg >> 6) * (2 * B_ * S_),
                (char*)&mask_lds[0][0] + buf * 1024 + w * 256);
  };

  int off[4];
#pragma unroll
  for (int x = 0; x < 4; ++x) off[x] = ((2 * x + hi) ^ l7) * 8;

  f32x16 oacc[2];
#pragma unroll
  for (int i = 0; i < 16; ++i) { oacc[0][i] = 0.f; oacc[1][i] = 0.f; }
  float la[4] = {0.f, 0.f, 0.f, 0.f};

  // prologue: stage tiles 0,1 into bufs 0,1 (10 VMEM ops in flight)
  stage(0, 0);
  stage(1, 64);

  int rb3 = 0, wb3 = 2;
  for (int kt = 0; kt < S_; kt += 64) {
    // issue tile kt+128 into the 3rd buffer (its readers finished two
    // iterations ago at the end-of-iter barrier)
    if (kt + 128 < S_) stage(wb3, kt + 128);

    // counted wait: tile kt's 5 ops done; newer 10 stay in flight
    if (kt + 128 < S_) {
      asm volatile("s_waitcnt vmcnt(10)" ::: "memory");
    } else if (kt + 64 < S_) {
      asm volatile("s_waitcnt vmcnt(5)" ::: "memory");
    } else {
      asm volatile("s_waitcnt vmcnt(0)" ::: "memory");
    }
    __builtin_amdgcn_s_barrier();  // all waves' tile-kt writes visible

    // mask word for this lane's q-row, keys [kt, kt+64)
    const unsigned long long mw = mask_lds[rb3][w * 32 + l31];
    const unsigned long long msh = mw >> (4 * hi);
    int inv[2];
    inv[0] = ~(int)(unsigned)msh;
    inv[1] = ~(int)(unsigned)(msh >> 32);

    // ---- S^T = K Q^T with mask bias folded into C-init:
    // sacc[g][reg] = (keep ? 0 : -200); key = 32g + (reg&3)+8*(reg>>2)+4hi
    bf16x8 kf[2][4];
#pragma unroll
    for (int g = 0; g < 2; ++g)
#pragma unroll
      for (int s = 0; s < 4; ++s)
        kf[g][s] = *(const bf16x8*)&k_s[rb3][(32 * g + l31) * 64 + off[s]];

    f32x16 sacc[2];
#pragma unroll
    for (int g = 0; g < 2; ++g)
#pragma unroll
      for (int reg = 0; reg < 16; ++reg) {
        const int base = (reg & 3) + 8 * (reg >> 2);
        const int sm = __builtin_amdgcn_sbfe(inv[g], base, 1);  // keep?0:-1
        sacc[g][reg] = __int_as_float(sm & 0xC3480000);         // 0 or -200.0f
      }

    __builtin_amdgcn_s_setprio(1);
#pragma unroll
    for (int g = 0; g < 2; ++g)
#pragma unroll
      for (int s = 0; s < 4; ++s)
        sacc[g] = __builtin_amdgcn_mfma_f32_32x32x16_bf16(kf[g][s], qf[s], sacc[g], 0, 0, 0);
    __builtin_amdgcn_s_setprio(0);

    // ---- exp2 (Q carries log2e; masked keys = exp2(s-200) -> 0), pack pairs
    unsigned pd[2][8];
#pragma unroll
    for (int g = 0; g < 2; ++g) {
      float p[16];
#pragma unroll
      for (int reg = 0; reg < 16; ++reg) {
        float e;
        asm("v_exp_f32 %0, %1" : "=v"(e) : "v"(sacc[g][reg]));
        p[reg] = e;
      }
#pragma unroll
      for (int reg = 0; reg < 16; ++reg) la[reg & 3] += p[reg];
#pragma unroll
      for (int r = 0; r < 8; ++r) {
        unsigned dst;
        asm("v_cvt_pk_bf16_f32 %0, %1, %2" : "=v"(dst) : "v"(p[2 * r]), "v"(p[2 * r + 1]));
        pd[g][r] = dst;
      }
    }

    // ---- permlane exchange -> PV A-frags; O += P V
#pragma unroll
    for (int tt = 0; tt < 4; ++tt) {
      const int g = tt >> 1, tp = tt & 1;
      unsigned x0 = pd[g][4 * tp + 0], x2 = pd[g][4 * tp + 2];
      unsigned x1 = pd[g][4 * tp + 1], x3 = pd[g][4 * tp + 3];
      asm("v_permlane32_swap_b32 %0, %1" : "+v"(x0), "+v"(x2));
      asm("v_permlane32_swap_b32 %0, %1" : "+v"(x1), "+v"(x3));
      union { unsigned u[4]; bf16x8 v; } pa;
      pa.u[0] = x0; pa.u[1] = x1; pa.u[2] = x2; pa.u[3] = x3;
      bf16x8 vb0 = *(const bf16x8*)&vt_s[rb3][l31 * 64 + off[tt]];
      bf16x8 vb1 = *(const bf16x8*)&vt_s[rb3][(32 + l31) * 64 + off[tt]];
      __builtin_amdgcn_s_setprio(1);
      oacc[0] = __builtin_amdgcn_mfma_f32_32x32x16_bf16(pa.v, vb0, oacc[0], 0, 0, 0);
      oacc[1] = __builtin_amdgcn_mfma_f32_32x32x16_bf16(pa.v, vb1, oacc[1], 0, 0, 0);
      __builtin_amdgcn_s_setprio(0);
    }

    // all my LDS reads complete, then block-wide "done reading buf[rb3]"
    asm volatile("s_waitcnt lgkmcnt(0)" ::: "memory");
    __builtin_amdgcn_s_barrier();

    rb3 = (rb3 == 2) ? 0 : rb3 + 1;
    wb3 = (wb3 == 2) ? 0 : wb3 + 1;
  }

  // ---- epilogue: l per q-row (lane & lane+32 halves), divide, store
  float l_acc = (la[0] + la[1]) + (la[2] + la[3]);
  l_acc += __shfl_xor(l_acc, 32);
  const float linv = 1.0f / l_acc;  // lane l31 holds inv-l for q-row l31
#pragma unroll
  for (int reg = 0; reg < 16; ++reg) {
    const int base = (reg & 3) + 8 * (reg >> 2);
    const float li = __shfl(linv, base + 4 * hi);
    const int qa = q0 + w * 32 + base + 4 * hi;
    const size_t ro = (rbq + qa) * DM + h * 64 + l31;
    Oa[ro] = (ushort)f2b(oacc[0][reg] * li);
    Oa[ro + 32] = (ushort)f2b(oacc[1][reg] * li);
  }
}

// ---------------------------------------------------------------------------
// Workspace = 56 MB exactly:
//   qc,kc,vc (3*NE u16) | Qp,Kp,Vt (3*NE u16) | 4 weights (4*NW u16)
//   attn output reuses qc; mask bit-words (1 MB) live at the head of d_out.
extern "C" void kernel_launch(void* const* d_in, const int* in_sizes, int n_in,
                              void* d_out, int out_size, void* d_ws, size_t ws_size,
                              hipStream_t stream) {
  const int* mask = (const int*)d_in[3];
  const float* bq = (const float*)d_in[5];
  const float* bk = (const float*)d_in[7];
  const float* bv = (const float*)d_in[9];
  const float* bo = (const float*)d_in[11];

  const size_t NE = (size_t)B_ * S_ * DM;  // 4M
  const size_t NW = (size_t)DM * DM;       // 1M

  ushort* qc = (ushort*)d_ws;
  ushort* kc = qc + NE;
  ushort* vc = kc + NE;
  ushort* Qp = vc + NE;
  ushort* Kp = Qp + NE;
  ushort* Vt = Kp + NE;
  ushort* Wqc = Vt + NE;
  ushort* Wkc = Wqc + NW;
  ushort* Wvc = Wkc + NW;
  ushort* Woc = Wvc + NW;
  unsigned long long* mbits = (unsigned long long*)d_out;  // 1 MB at head of out

  Cvt7 c;
  const int sidx[7] = {0, 1, 2, 4, 6, 8, 10};
  ushort* dsts[7] = {qc, kc, vc, Wqc, Wkc, Wvc, Woc};
  for (int i = 0; i < 7; ++i) {
    c.src[i] = (const float*)d_in[sidx[i]];
    c.dst[i] = dsts[i];
    c.n[i] = (i < 3) ? (int)NE : (int)NW;
  }
  cvt_all<<<dim3(2048, 8), 256, 0, stream>>>(c, mask, mbits);

  // Q projection pre-scaled by (1/sqrt(dk)) * log2(e) so attn uses exp2
  G3 g;
  g.A[0] = qc;  g.A[1] = kc;  g.A[2] = vc;
  g.W[0] = Wqc; g.W[1] = Wkc; g.W[2] = Wvc;
  g.bias[0] = bq; g.bias[1] = bk; g.bias[2] = bv;
  g.C[0] = Qp;  g.C[1] = Kp;  g.C[2] = Vt;
  g.scale[0] = 0.125f * 1.4426950408889634f;
  g.scale[1] = 1.0f;
  g.scale[2] = 1.0f;
  gemm_qkv<<<dim3(Mdim / 128, Ndim / 128, 3), 256, 0, stream>>>(g);

  attn_mfma<<<dim3(512), 256, 0, stream>>>(Qp, Kp, Vt, mbits, qc);

  gemm128<float><<<dim3(Mdim / 128, Ndim / 64), 256, 0, stream>>>(
      qc, Woc, bo, (float*)d_out, 1.0f);
}